// Round 5
// baseline (513.845 us; speedup 1.0000x reference)
//
#include <hip/hip_runtime.h>

#define N_NODES 100000
#define N_EDGES 800000
#define NF 81
#define NB 22
#define OC 64
#define PAD 8
#define MAXSLOTS (N_EDGES + (PAD - 1) * N_NODES)   // 1,500,000 worst case
#define SCAN_CHUNK 1024
#define SCAN_BLOCKS ((N_NODES + SCAN_CHUNK - 1) / SCAN_CHUNK)   // 98

// ---------------------------------------------------------------------------
// Fused node GEMM: out = feat@w_s ; pb = feat@w_n[:81] ; xyz packed.
// LDS-tiled: 64 nodes/block, lane = node, wave = 16 channels.
// Feat tile staged via coalesced float4 -> LDS; weights via wave-uniform
// s_loads (k-step batches); 2x16 fmacs per k per thread. VALU-bound.
__global__ __launch_bounds__(256) void k_node2(
    const float* __restrict__ feat, const float* __restrict__ w_s,
    const float* __restrict__ w_n, float* __restrict__ out,
    float* __restrict__ pb, float4* __restrict__ xyz)
{
    __shared__ float sh[64 * NF];                 // 20736 B
    const int t  = threadIdx.x;
    const int n0 = blockIdx.x * 64;

    // --- stage tile (coalesced float4; base is 16B aligned since 64*81%4==0)
    const float4* gsrc = (const float4*)(feat + (long)n0 * NF);
    float4* shv = (float4*)sh;
    const int NV = (64 * NF) / 4;                 // 1296
    const int limv = (int)(((long)N_NODES * NF) / 4 - (long)n0 * NF / 4);
    for (int i = t; i < NV; i += 256)
        shv[i] = (i < limv) ? gsrc[i] : make_float4(0.f, 0.f, 0.f, 0.f);
    __syncthreads();

    const int lane = t & 63;                      // node within tile
    const int wv   = t >> 6;                      // wave 0..3
    const int cb   = wv * 16;                     // channel base
    const float* fr = sh + lane * NF;             // stride 81 -> conflict-free

    float accs[16], accn[16];
#pragma unroll
    for (int q = 0; q < 16; ++q) { accs[q] = 0.f; accn[q] = 0.f; }

    for (int k0 = 0; k0 < 80; k0 += 2) {
        const float f0 = fr[k0], f1 = fr[k0 + 1];
        float ws0[16], ws1[16], wn0[16], wn1[16];
#pragma unroll
        for (int q = 0; q < 16; ++q) {            // wave-uniform -> s_loads
            ws0[q] = w_s[(k0    ) * OC + cb + q];
            ws1[q] = w_s[(k0 + 1) * OC + cb + q];
            wn0[q] = w_n[(k0    ) * OC + cb + q];
            wn1[q] = w_n[(k0 + 1) * OC + cb + q];
        }
#pragma unroll
        for (int q = 0; q < 16; ++q) {
            accs[q] += f0 * ws0[q] + f1 * ws1[q];
            accn[q] += f0 * wn0[q] + f1 * wn1[q];
        }
    }
    {   // k = 80 tail
        const float f0 = fr[80];
#pragma unroll
        for (int q = 0; q < 16; ++q) {
            accs[q] += f0 * w_s[80 * OC + cb + q];
            accn[q] += f0 * w_n[80 * OC + cb + q];
        }
    }

    const int node = n0 + lane;
    if (node < N_NODES) {
        float4* po = (float4*)(out + (long)node * OC + cb);
        float4* pp = (float4*)(pb  + (long)node * OC + cb);
#pragma unroll
        for (int q = 0; q < 4; ++q) {
            po[q] = make_float4(accs[4*q], accs[4*q+1], accs[4*q+2], accs[4*q+3]);
            pp[q] = make_float4(accn[4*q], accn[4*q+1], accn[4*q+2], accn[4*q+3]);
        }
        if (wv == 0)
            xyz[node] = make_float4(fr[0], fr[1], fr[2], 0.f);
    }
}

// ---------------------------------------------------------------------------
__global__ void k_hist(const int* __restrict__ src, int* __restrict__ cnt) {
    const int e = blockIdx.x * blockDim.x + threadIdx.x;
    if (e < N_EDGES) atomicAdd(&cnt[src[e]], 1);
}

// Padded scan: each node's CSR region rounded up to a multiple of 8.
__global__ __launch_bounds__(256) void k_scan_blk(
    const int* __restrict__ cnt, int* __restrict__ row, int* __restrict__ bsum)
{
    __shared__ int sh[256];
    const int t = threadIdx.x;
    const int base = blockIdx.x * SCAN_CHUNK + t * 4;
    int c0 = 0, c1 = 0, c2 = 0, c3 = 0;
    if (base + 3 < N_NODES) {
        const int4 c = *(const int4*)(cnt + base);
        c0 = c.x; c1 = c.y; c2 = c.z; c3 = c.w;
    } else {
        if (base + 0 < N_NODES) c0 = cnt[base + 0];
        if (base + 1 < N_NODES) c1 = cnt[base + 1];
        if (base + 2 < N_NODES) c2 = cnt[base + 2];
    }
    const int p0 = (c0 + 7) & ~7, p1 = (c1 + 7) & ~7;
    const int p2 = (c2 + 7) & ~7, p3 = (c3 + 7) & ~7;
    const int s = p0 + p1 + p2 + p3;
    sh[t] = s;
    __syncthreads();
    for (int off = 1; off < 256; off <<= 1) {
        int v = sh[t];
        int a = (t >= off) ? sh[t - off] : 0;
        __syncthreads();
        sh[t] = v + a;
        __syncthreads();
    }
    const int excl = sh[t] - s;
    if (t == 255) bsum[blockIdx.x] = sh[255];
    if (base + 3 < N_NODES) {
        int4 r;
        r.x = excl; r.y = excl + p0; r.z = excl + p0 + p1; r.w = excl + p0 + p1 + p2;
        *(int4*)(row + base) = r;
    } else {
        int e = excl;
        if (base + 0 < N_NODES) { row[base + 0] = e; e += p0; }
        if (base + 1 < N_NODES) { row[base + 1] = e; e += p1; }
        if (base + 2 < N_NODES) { row[base + 2] = e; }
    }
}

__global__ void k_scan_top(int* __restrict__ bsum, int* __restrict__ row) {
    __shared__ int sh[128];
    const int t = threadIdx.x;
    const int v = (t < SCAN_BLOCKS) ? bsum[t] : 0;
    sh[t] = v;
    __syncthreads();
    for (int off = 1; off < 128; off <<= 1) {
        int x = sh[t];
        int a = (t >= off) ? sh[t - off] : 0;
        __syncthreads();
        sh[t] = x + a;
        __syncthreads();
    }
    if (t < SCAN_BLOCKS) bsum[t] = sh[t] - v;
    if (t == 127) row[N_NODES] = sh[127];
}

__global__ __launch_bounds__(256) void k_scan_add(
    int* __restrict__ row, int* __restrict__ cursor, const int* __restrict__ bsum)
{
    const int off = bsum[blockIdx.x];
    const int base = blockIdx.x * SCAN_CHUNK + threadIdx.x * 4;
    if (base + 3 < N_NODES) {
        int4 r = *(const int4*)(row + base);
        r.x += off; r.y += off; r.z += off; r.w += off;
        *(int4*)(row + base) = r;
        *(int4*)(cursor + base) = r;
    } else {
#pragma unroll
        for (int k = 0; k < 4; ++k)
            if (base + k < N_NODES) {
                const int v = row[base + k] + off;
                row[base + k] = v;
                cursor[base + k] = v;
            }
    }
}

// Zero the pad slots (inv=0 => zero contribution; ids 0 => safe addresses).
__global__ void k_pad(const int* __restrict__ row, const int* __restrict__ cnt,
                      int* __restrict__ sid, int* __restrict__ tid,
                      float* __restrict__ tinv)
{
    const int n = blockIdx.x * blockDim.x + threadIdx.x;
    if (n >= N_NODES) return;
    const int a = row[n] + cnt[n];
    const int b = row[n + 1];
    for (int i = a; i < b; ++i) {
        sid[i] = 0; tid[i] = 0; tinv[i] = 0.f;
    }
}

// Scatter: payload {edge id, dst, inv} into src-sorted padded CSR slots.
__global__ void k_prep(const int* __restrict__ src, const int* __restrict__ dst,
                       const float4* __restrict__ xyz, int* __restrict__ cursor,
                       int* __restrict__ sid, int* __restrict__ tid,
                       float* __restrict__ tinv)
{
    const int e = blockIdx.x * blockDim.x + threadIdx.x;
    if (e >= N_EDGES) return;
    const int s = src[e];
    const int t = dst[e];
    const float4 a = xyz[s], b = xyz[t];
    const float dx = a.x - b.x, dy = a.y - b.y, dz = a.z - b.z;
    const float d2 = dx * dx + dy * dy + dz * dz;
    const float inv = (d2 > 0.f) ? __builtin_amdgcn_rcpf(d2) : 1.0e4f;
    const int pos = atomicAdd(&cursor[s], 1);
    sid[pos] = e;
    tid[pos] = t;
    tinv[pos] = inv;
}

// Per-node bond segment-sum: bond_agg[n][0:22] = sum of bond rows of n's edges.
// Wave per node; lanes 0..21 vector-load each row; 8 ids per s_load batch.
__global__ __launch_bounds__(256) void k_bondagg(
    const int* __restrict__ row, const int* __restrict__ cnt,
    const int* __restrict__ sid, const float* __restrict__ bond,
    float* __restrict__ bond_agg)
{
    const int lane = threadIdx.x & 63;
    const int n = (int)((blockIdx.x * blockDim.x + threadIdx.x) >> 6);
    if (n >= N_NODES) return;
    const int rs = row[n], re = row[n + 1];
    const int c  = cnt[n];
    float a = 0.f;
    for (int i = rs; i < re; i += 8) {
        int e[8];
#pragma unroll
        for (int k = 0; k < 8; ++k) e[k] = sid[i + k];   // s_load_dwordx8
#pragma unroll
        for (int k = 0; k < 8; ++k) {
            const float v = (lane < NB) ? bond[(long)e[k] * NB + lane] : 0.f;
            a += ((i + k) < (rs + c)) ? v : 0.f;
        }
    }
    if (lane < NB) bond_agg[(long)n * NB + lane] = a;
}

// Gather: wave per node, lane = channel, no atomics, 2-hop chain:
// s_load {tid,inv}x8 -> 8 parallel pb gathers. Bond term: 22 fmacs from
// bond_agg (s_load, independent of the chain). sum identity:
// sum (pa+pb_t)*inv = pa*sum(inv) + sum(inv*pb_t).
__global__ __launch_bounds__(256) void k_gather(
    const int* __restrict__ row, const int* __restrict__ tid,
    const float* __restrict__ tinv, const float* __restrict__ bond_agg,
    const float* __restrict__ w_n, const float* __restrict__ pb,
    const float4* __restrict__ xyz, float* __restrict__ out)
{
    const int lane = threadIdx.x & 63;
    const int n = (int)((blockIdx.x * blockDim.x + threadIdx.x) >> 6);
    if (n >= N_NODES) return;

    float wnb[NB];
#pragma unroll
    for (int j = 0; j < NB; ++j) wnb[j] = w_n[(NF + j) * OC + lane];
    const float w0 = w_n[0 * OC + lane];
    const float w1 = w_n[1 * OC + lane];
    const float w2 = w_n[2 * OC + lane];

    const int rs = row[n], re = row[n + 1];
    const float4 xs = xyz[n];
    const float pa = pb[(long)n * OC + lane]
                   - (xs.x * w0 + xs.y * w1 + xs.z * w2);

    float acc = 0.f, sinv = 0.f;
    for (int i = rs; i < re; i += 8) {
        int tt[8]; float iv[8];
#pragma unroll
        for (int k = 0; k < 8; ++k) tt[k] = tid[i + k];    // s_load_dwordx8
#pragma unroll
        for (int k = 0; k < 8; ++k) iv[k] = tinv[i + k];   // s_load_dwordx8
        float pbt[8];
#pragma unroll
        for (int k = 0; k < 8; ++k)                         // 8 parallel gathers
            pbt[k] = pb[(long)tt[k] * OC + lane];
#pragma unroll
        for (int k = 0; k < 8; ++k) { acc += iv[k] * pbt[k]; sinv += iv[k]; }
    }

    float bag[NB];
#pragma unroll
    for (int j = 0; j < NB; ++j) bag[j] = bond_agg[(long)n * NB + j]; // s_loads
    float bacc = 0.f;
#pragma unroll
    for (int j = 0; j < NB; ++j) bacc += bag[j] * wnb[j];

    out[(long)n * OC + lane] += acc + pa * sinv + bacc;
}

// ---------------------------------------------------------------------------
extern "C" void kernel_launch(void* const* d_in, const int* in_sizes, int n_in,
                              void* d_out, int out_size, void* d_ws, size_t ws_size,
                              hipStream_t stream) {
    const float* feat = (const float*)d_in[0];
    const float* bond = (const float*)d_in[1];
    const float* w_s  = (const float*)d_in[2];
    const float* w_n  = (const float*)d_in[3];
    const int*   src  = (const int*)d_in[4];
    const int*   dstv = (const int*)d_in[5];
    float* out = (float*)d_out;

    // workspace layout (16B-aligned), ~55.2 MB total
    char* base = (char*)d_ws;
    float*  pb       = (float*) (base);                    // 25,600,000
    float4* xyz      = (float4*)(base + 25600000);         //  1,600,000
    int*    row      = (int*)   (base + 27200000);         //    400,016
    int*    cnt      = (int*)   (base + 27600016);         //    400,000
    int*    cursor   = (int*)   (base + 28000016);         //    400,000
    int*    sid      = (int*)   (base + 28400016);         //  6,000,000
    int*    tid      = (int*)   (base + 34400016);         //  6,000,000
    float*  tinv     = (float*) (base + 40400016);         //  6,000,000
    float*  bond_agg = (float*) (base + 46400016);         //  8,800,000
    int*    bsum     = (int*)   (base + 55200016);         //        512

    hipMemsetAsync(cnt, 0, N_NODES * sizeof(int), stream);

    k_node2   <<<(N_NODES + 63) / 64, 256, 0, stream>>>(feat, w_s, w_n, out, pb, xyz);
    k_hist    <<<(N_EDGES + 255) / 256, 256, 0, stream>>>(src, cnt);
    k_scan_blk<<<SCAN_BLOCKS, 256, 0, stream>>>(cnt, row, bsum);
    k_scan_top<<<1, 128, 0, stream>>>(bsum, row);
    k_scan_add<<<SCAN_BLOCKS, 256, 0, stream>>>(row, cursor, bsum);
    k_pad     <<<(N_NODES + 255) / 256, 256, 0, stream>>>(row, cnt, sid, tid, tinv);
    k_prep    <<<(N_EDGES + 255) / 256, 256, 0, stream>>>(src, dstv, xyz, cursor,
                                                          sid, tid, tinv);
    k_bondagg <<<(N_NODES * 64 + 255) / 256, 256, 0, stream>>>(row, cnt, sid, bond,
                                                               bond_agg);
    k_gather  <<<(N_NODES * 64 + 255) / 256, 256, 0, stream>>>(row, tid, tinv,
                                                               bond_agg, w_n, pb,
                                                               xyz, out);
}

// Round 6
// 377.951 us; speedup vs baseline: 1.3596x; 1.3596x over previous
//
#include <hip/hip_runtime.h>

#define N_NODES 100000
#define N_EDGES 800000
#define NF 81
#define NB 22
#define OC 64
#define SCAN_CHUNK 1024
#define SCAN_BLOCKS ((N_NODES + SCAN_CHUNK - 1) / SCAN_CHUNK)   // 98
#define ASTRIDE 68                    // LDS A-tile stride: 16B-aligned, conflict-lite

// ---------------------------------------------------------------------------
// Fused node GEMM (out = feat@w_s, pb = feat@w_n[:81], xyz packed).
// Classic LDS-tiled GEMM: 64 nodes x 128 channels per block.
//  - A staged TRANSPOSED: shA[k][n] (stride 68 -> ds_read_b128 aligned)
//  - both weights staged: shW[k][0:128] = [w_s[k] | w_n[k]]
//  - thread (tx=t&15, ty=t>>4) computes 4 nodes x 8 channels in registers.
// R5 failure mode fixed: no reliance on the compiler proving wave-uniformity;
// everything is plain LDS reads + fmacs. VALU floor ~13 us.
__global__ __launch_bounds__(256) void k_node3(
    const float* __restrict__ feat, const float* __restrict__ w_s,
    const float* __restrict__ w_n, float* __restrict__ out,
    float* __restrict__ pb, float4* __restrict__ xyz)
{
    __shared__ float shA[NF * ASTRIDE];   // 81*68*4 = 22,032 B
    __shared__ float shW[NF * 128];       // 81*128*4 = 41,472 B
    const int t  = threadIdx.x;
    const int n0 = blockIdx.x * 64;

    // stage W (coalesced global, linear LDS)
    for (int idx = t; idx < NF * OC; idx += 256) {
        const int k = idx >> 6, c = idx & 63;
        shW[k * 128 + c]      = w_s[idx];
        shW[k * 128 + 64 + c] = w_n[idx];
    }
    // stage A transposed (coalesced global: n0*81+f is contiguous)
    const long gbase = (long)n0 * NF;
    for (int f = t; f < 64 * NF; f += 256) {
        const int n = f / NF;
        const int k = f - n * NF;
        const float v = (gbase + f < (long)N_NODES * NF) ? feat[gbase + f] : 0.f;
        shA[k * ASTRIDE + n] = v;
    }
    __syncthreads();

    if (t < 64 && n0 + t < N_NODES)
        xyz[n0 + t] = make_float4(shA[0 * ASTRIDE + t], shA[1 * ASTRIDE + t],
                                  shA[2 * ASTRIDE + t], 0.f);

    const int tx = t & 15;                // node group: nodes tx*4..tx*4+3
    const int ty = t >> 4;                // channel group: ty*8..ty*8+7
    float acc[32];
#pragma unroll
    for (int q = 0; q < 32; ++q) acc[q] = 0.f;

    const float* ap = shA + tx * 4;
    const float* wp = shW + ty * 8;
#pragma unroll 3
    for (int k = 0; k < NF; ++k) {
        const float4 a  = *(const float4*)(ap + k * ASTRIDE);
        const float4 w0 = *(const float4*)(wp + k * 128);
        const float4 w1 = *(const float4*)(wp + k * 128 + 4);
        const float av[4] = {a.x, a.y, a.z, a.w};
        const float wv[8] = {w0.x, w0.y, w0.z, w0.w, w1.x, w1.y, w1.z, w1.w};
#pragma unroll
        for (int i = 0; i < 4; ++i)
#pragma unroll
            for (int j = 0; j < 8; ++j)
                acc[i * 8 + j] += av[i] * wv[j];
    }

    // epilogue: ty<8 -> out channels ty*8..+7 ; ty>=8 -> pb channels (ty-8)*8..
    float* dbase = (ty < 8) ? out : pb;
    const int cb = (ty & 7) * 8;
#pragma unroll
    for (int i = 0; i < 4; ++i) {
        const int node = n0 + tx * 4 + i;
        if (node < N_NODES) {
            float* p = dbase + (long)node * OC + cb;
            *(float4*)(p)     = make_float4(acc[i*8+0], acc[i*8+1], acc[i*8+2], acc[i*8+3]);
            *(float4*)(p + 4) = make_float4(acc[i*8+4], acc[i*8+5], acc[i*8+6], acc[i*8+7]);
        }
    }
}

// ---------------------------------------------------------------------------
__global__ void k_hist(const int* __restrict__ src, int* __restrict__ cnt) {
    const int e = blockIdx.x * blockDim.x + threadIdx.x;
    if (e < N_EDGES) atomicAdd(&cnt[src[e]], 1);
}

__global__ __launch_bounds__(256) void k_scan_blk(
    const int* __restrict__ cnt, int* __restrict__ row, int* __restrict__ bsum)
{
    __shared__ int sh[256];
    const int t = threadIdx.x;
    const int base = blockIdx.x * SCAN_CHUNK + t * 4;
    int c0 = 0, c1 = 0, c2 = 0, c3 = 0;
    if (base + 3 < N_NODES) {
        const int4 c = *(const int4*)(cnt + base);
        c0 = c.x; c1 = c.y; c2 = c.z; c3 = c.w;
    } else {
        if (base + 0 < N_NODES) c0 = cnt[base + 0];
        if (base + 1 < N_NODES) c1 = cnt[base + 1];
        if (base + 2 < N_NODES) c2 = cnt[base + 2];
    }
    const int s = c0 + c1 + c2 + c3;
    sh[t] = s;
    __syncthreads();
    for (int off = 1; off < 256; off <<= 1) {
        int v = sh[t];
        int a = (t >= off) ? sh[t - off] : 0;
        __syncthreads();
        sh[t] = v + a;
        __syncthreads();
    }
    const int excl = sh[t] - s;
    if (t == 255) bsum[blockIdx.x] = sh[255];
    if (base + 3 < N_NODES) {
        int4 r;
        r.x = excl; r.y = excl + c0; r.z = excl + c0 + c1; r.w = excl + c0 + c1 + c2;
        *(int4*)(row + base) = r;
    } else {
        int e = excl;
        if (base + 0 < N_NODES) { row[base + 0] = e; e += c0; }
        if (base + 1 < N_NODES) { row[base + 1] = e; e += c1; }
        if (base + 2 < N_NODES) { row[base + 2] = e; }
    }
}

__global__ void k_scan_top(int* __restrict__ bsum, int* __restrict__ row) {
    __shared__ int sh[128];
    const int t = threadIdx.x;
    const int v = (t < SCAN_BLOCKS) ? bsum[t] : 0;
    sh[t] = v;
    __syncthreads();
    for (int off = 1; off < 128; off <<= 1) {
        int x = sh[t];
        int a = (t >= off) ? sh[t - off] : 0;
        __syncthreads();
        sh[t] = x + a;
        __syncthreads();
    }
    if (t < SCAN_BLOCKS) bsum[t] = sh[t] - v;
    if (t == 127) row[N_NODES] = sh[127];
}

__global__ __launch_bounds__(256) void k_scan_add(
    int* __restrict__ row, int* __restrict__ cursor, const int* __restrict__ bsum)
{
    const int off = bsum[blockIdx.x];
    const int base = blockIdx.x * SCAN_CHUNK + threadIdx.x * 4;
    if (base + 3 < N_NODES) {
        int4 r = *(const int4*)(row + base);
        r.x += off; r.y += off; r.z += off; r.w += off;
        *(int4*)(row + base) = r;
        *(int4*)(cursor + base) = r;
    } else {
#pragma unroll
        for (int k = 0; k < 4; ++k)
            if (base + k < N_NODES) {
                const int v = row[base + k] + off;
                row[base + k] = v;
                cursor[base + k] = v;
            }
    }
}

// ---------------------------------------------------------------------------
// Scatter one 64B record per edge into src-sorted slot:
//  dw[0..10]  = bond[0..21] packed as bf16 pairs (RNE-ish bias)
//  dw[11]     = inv (f32)          dw[12] = dst id        dw[13..15] unused
// Bond reads are coalesced (edge order); record write is 3x16B + 8B.
__device__ inline unsigned pk_bf16(float a, float b) {
    const unsigned ua = (__float_as_uint(a) + 0x8000u) >> 16;
    const unsigned ub = (__float_as_uint(b) + 0x8000u) & 0xffff0000u;
    return ua | ub;
}

__global__ void k_prep(const int* __restrict__ src, const int* __restrict__ dst,
                       const float* __restrict__ bond, const float4* __restrict__ xyz,
                       int* __restrict__ cursor, unsigned* __restrict__ rec)
{
    const int e = blockIdx.x * blockDim.x + threadIdx.x;
    if (e >= N_EDGES) return;
    const int s = src[e];
    const int d = dst[e];
    const float4 a = xyz[s], b = xyz[d];
    const float dx = a.x - b.x, dy = a.y - b.y, dz = a.z - b.z;
    const float d2 = dx * dx + dy * dy + dz * dz;
    const float inv = (d2 > 0.f) ? __builtin_amdgcn_rcpf(d2) : 1.0e4f;

    float bv[NB];
    const float2* bp = (const float2*)(bond + (long)e * NB);   // 88B, 8B-aligned
#pragma unroll
    for (int j = 0; j < NB / 2; ++j) {
        const float2 v = bp[j];
        bv[2 * j] = v.x; bv[2 * j + 1] = v.y;
    }

    unsigned p[11];
#pragma unroll
    for (int j = 0; j < 11; ++j) p[j] = pk_bf16(bv[2 * j], bv[2 * j + 1]);

    const int pos = atomicAdd(&cursor[s], 1);
    unsigned* r = rec + (size_t)pos * 16;
    *(uint4*)(r)     = make_uint4(p[0], p[1], p[2], p[3]);
    *(uint4*)(r + 4) = make_uint4(p[4], p[5], p[6], p[7]);
    *(uint4*)(r + 8) = make_uint4(p[8], p[9], p[10], __float_as_uint(inv));
    *(uint2*)(r + 12) = make_uint2((unsigned)d, 0u);
}

// ---------------------------------------------------------------------------
// Gather: wave per node, lane = channel, NO atomics.
// Records read sequentially at wave-uniform addresses -> batched s_loads;
// bf16 unpack runs on the scalar pipe; per edge: 22 fmacs + 1 pb gather.
__global__ __launch_bounds__(256) void k_gather(
    const int* __restrict__ row, const unsigned* __restrict__ rec,
    const float* __restrict__ w_n, const float* __restrict__ pb,
    const float4* __restrict__ xyz, float* __restrict__ out)
{
    const int lane = threadIdx.x & 63;
    const int wid  = (int)((blockIdx.x * blockDim.x + threadIdx.x) >> 6);
    if (wid >= N_NODES) return;
    const int n = __builtin_amdgcn_readfirstlane(wid);

    float wnb[NB];
#pragma unroll
    for (int j = 0; j < NB; ++j) wnb[j] = w_n[(NF + j) * OC + lane];
    const float w0 = w_n[0 * OC + lane];
    const float w1 = w_n[1 * OC + lane];
    const float w2 = w_n[2 * OC + lane];

    const int rs = row[n], re = row[n + 1];
    const float4 xs = xyz[n];
    const float pa = pb[(long)n * OC + lane]
                   - (xs.x * w0 + xs.y * w1 + xs.z * w2);

    float acc = 0.f;
    int i = rs;
    for (; i + 2 <= re; i += 2) {
        const unsigned* rA = rec + (size_t)i * 16;
        const unsigned* rB = rA + 16;
        unsigned pA[13], pB[13];
#pragma unroll
        for (int j = 0; j < 13; ++j) pA[j] = rA[j];   // s_load batch
#pragma unroll
        for (int j = 0; j < 13; ++j) pB[j] = rB[j];
        const float invA = __uint_as_float(pA[11]);
        const float invB = __uint_as_float(pB[11]);
        const int   tA   = (int)pA[12];
        const int   tB   = (int)pB[12];
        const float pbtA = pb[(long)tA * OC + lane];
        const float pbtB = pb[(long)tB * OC + lane];

        float cA = invA * (pa + pbtA);
        float cB = invB * (pa + pbtB);
#pragma unroll
        for (int j = 0; j < 11; ++j) {
            cA += __uint_as_float(pA[j] << 16)        * wnb[2 * j]
                + __uint_as_float(pA[j] & 0xffff0000u) * wnb[2 * j + 1];
            cB += __uint_as_float(pB[j] << 16)        * wnb[2 * j]
                + __uint_as_float(pB[j] & 0xffff0000u) * wnb[2 * j + 1];
        }
        acc += cA + cB;
    }
    if (i < re) {   // tail edge
        const unsigned* r = rec + (size_t)i * 16;
        unsigned p[13];
#pragma unroll
        for (int j = 0; j < 13; ++j) p[j] = r[j];
        const float inv = __uint_as_float(p[11]);
        const int   tt  = (int)p[12];
        const float pbt = pb[(long)tt * OC + lane];
        float c = inv * (pa + pbt);
#pragma unroll
        for (int j = 0; j < 11; ++j)
            c += __uint_as_float(p[j] << 16)        * wnb[2 * j]
               + __uint_as_float(p[j] & 0xffff0000u) * wnb[2 * j + 1];
        acc += c;
    }

    out[(long)n * OC + lane] += acc;
}

// ---------------------------------------------------------------------------
extern "C" void kernel_launch(void* const* d_in, const int* in_sizes, int n_in,
                              void* d_out, int out_size, void* d_ws, size_t ws_size,
                              hipStream_t stream) {
    const float* feat = (const float*)d_in[0];
    const float* bond = (const float*)d_in[1];
    const float* w_s  = (const float*)d_in[2];
    const float* w_n  = (const float*)d_in[3];
    const int*   src  = (const int*)d_in[4];
    const int*   dstv = (const int*)d_in[5];
    float* out = (float*)d_out;

    // workspace layout (64B-aligned), ~79.6 MB total
    char* base = (char*)d_ws;
    float*    pb     = (float*)   (base);                 // 25,600,000
    float4*   xyz    = (float4*)  (base + 25600000);      //  1,600,000
    int*      row    = (int*)     (base + 27200000);      //    400,016
    int*      cnt    = (int*)     (base + 27600016);      //    400,000
    int*      cursor = (int*)     (base + 28000016);      //    400,000
    int*      bsum   = (int*)     (base + 28400016);      //        560 (pad)
    unsigned* rec    = (unsigned*)(base + 28400576);      // 51,200,000

    hipMemsetAsync(cnt, 0, N_NODES * sizeof(int), stream);

    k_node3   <<<(N_NODES + 63) / 64, 256, 0, stream>>>(feat, w_s, w_n, out, pb, xyz);
    k_hist    <<<(N_EDGES + 255) / 256, 256, 0, stream>>>(src, cnt);
    k_scan_blk<<<SCAN_BLOCKS, 256, 0, stream>>>(cnt, row, bsum);
    k_scan_top<<<1, 128, 0, stream>>>(bsum, row);
    k_scan_add<<<SCAN_BLOCKS, 256, 0, stream>>>(row, cursor, bsum);
    k_prep    <<<(N_EDGES + 255) / 256, 256, 0, stream>>>(src, dstv, bond, xyz,
                                                          cursor, rec);
    k_gather  <<<(N_NODES * 64 + 255) / 256, 256, 0, stream>>>(row, rec, w_n, pb,
                                                               xyz, out);
}